// Round 2
// baseline (1206.668 us; speedup 1.0000x reference)
//
#include <hip/hip_runtime.h>
#include <hip/hip_fp16.h>
#include <cstdint>
#include <cstddef>

// MoE FFN, D=512 F=2048 E=8 K=2, N=32768 tokens. fp16 MFMA.
// Fused GEMM1+GELU+GEMM2, h in LDS. 16 waves/block, W2 direct global->VGPR
// (no LDS staging, prefetched across raw barriers), padded LDS strides
// (conflict-free), phase B barrier-free.
#define NTOK 32768
#define DM 512
#define FF 2048
#define NE 8
#define BM 128
#define FBLK 128
#define NFB (FF / FBLK)
#define XS_STRIDE 40   // 32 halfs + 8 pad: 80B rows -> uniform bank quads
#define HS_STRIDE 136  // 128 halfs + 8 pad: 272B rows -> uniform bank quads
#define SBUF (BM * XS_STRIDE)

typedef _Float16 half8 __attribute__((ext_vector_type(8)));
typedef float floatx4 __attribute__((ext_vector_type(4)));

#define LGKM0_BARRIER() do { \
  asm volatile("s_waitcnt lgkmcnt(0)" ::: "memory"); \
  __builtin_amdgcn_s_barrier(); \
} while (0)

// ---------------- transpose + fp32->fp16 cast: W (E,R,C) -> Wt (E,C,R) ----------------
__global__ __launch_bounds__(256) void k_transpose(const float* __restrict__ W,
                                                   _Float16* __restrict__ Wt, int R, int C) {
  __shared__ float tile[32][33];
  int e = blockIdx.z;
  int c0 = blockIdx.x * 32, r0 = blockIdx.y * 32;
  const float* Wp = W + (size_t)e * R * C;
  _Float16* Wtp = Wt + (size_t)e * R * C;
  int tx = threadIdx.x & 31, ty = threadIdx.x >> 5;
  #pragma unroll
  for (int rr = ty; rr < 32; rr += 8)
    tile[rr][tx] = Wp[(size_t)(r0 + rr) * C + c0 + tx];
  __syncthreads();
  #pragma unroll
  for (int cc = ty; cc < 32; cc += 8)
    Wtp[(size_t)(c0 + cc) * R + r0 + tx] = (_Float16)tile[tx][cc];
}

// ---------------- router: logits, top-2, softmax weights, aux accumulators, x->f16 ----------------
__global__ __launch_bounds__(256) void k_router(
    const float* __restrict__ x, const float* __restrict__ rw,
    _Float16* __restrict__ xb, int* __restrict__ route_e, float* __restrict__ route_w,
    int* __restrict__ counts, float* __restrict__ aux_acc) {
  __shared__ float s_p[NE];
  __shared__ float s_c[NE];
  __shared__ int s_cnt[NE];
  int tid = threadIdx.x, lane = tid & 63, wave = tid >> 6;
  if (tid < NE) { s_p[tid] = 0.f; s_c[tid] = 0.f; s_cnt[tid] = 0; }
  __syncthreads();
  int n = blockIdx.x * 4 + wave;  // one wave per token
  const float4* xr = (const float4*)(x + (size_t)n * DM + lane * 8);
  float4 x0 = xr[0], x1 = xr[1];
  float xv[8] = {x0.x, x0.y, x0.z, x0.w, x1.x, x1.y, x1.z, x1.w};
  float acc[NE];
  #pragma unroll
  for (int e = 0; e < NE; e++) acc[e] = 0.f;
  const float4* rwv = (const float4*)rw;  // (D, E=8) row-major: 2 float4 per row
  #pragma unroll
  for (int j = 0; j < 8; j++) {
    int d = lane * 8 + j;
    float4 r0 = rwv[d * 2], r1 = rwv[d * 2 + 1];
    float xd = xv[j];
    acc[0] += xd * r0.x; acc[1] += xd * r0.y; acc[2] += xd * r0.z; acc[3] += xd * r0.w;
    acc[4] += xd * r1.x; acc[5] += xd * r1.y; acc[6] += xd * r1.z; acc[7] += xd * r1.w;
  }
  half8 hv;
  #pragma unroll
  for (int j = 0; j < 8; j++) hv[j] = (_Float16)xv[j];
  *(half8*)(xb + (size_t)n * DM + lane * 8) = hv;
  #pragma unroll
  for (int e = 0; e < NE; e++) {
    #pragma unroll
    for (int m = 1; m < 64; m <<= 1) acc[e] += __shfl_xor(acc[e], m);
  }
  if (lane == 0) {
    int e0 = 0; float v0 = acc[0];
    for (int e = 1; e < NE; e++) if (acc[e] > v0) { v0 = acc[e]; e0 = e; }
    int e1 = (e0 == 0) ? 1 : 0; float v1 = acc[e1];
    for (int e = 0; e < NE; e++) if (e != e0 && acc[e] > v1) { v1 = acc[e]; e1 = e; }
    float w0 = 1.f / (1.f + expf(v1 - v0));
    float w1 = 1.f - w0;
    route_e[n] = e0 | (e1 << 8);
    route_w[2 * n] = w0; route_w[2 * n + 1] = w1;
    float mx = acc[0];
    for (int e = 1; e < NE; e++) mx = fmaxf(mx, acc[e]);
    float p[NE]; float s = 0.f;
    for (int e = 0; e < NE; e++) { p[e] = expf(acc[e] - mx); s += p[e]; }
    float inv = 1.f / s;
    atomicAdd(&s_cnt[e0], 1); atomicAdd(&s_cnt[e1], 1);
    for (int e = 0; e < NE; e++) atomicAdd(&s_p[e], p[e] * inv);
    atomicAdd(&s_c[e0], 1.f);
  }
  __syncthreads();
  if (tid < NE) {
    atomicAdd(&counts[tid], s_cnt[tid]);
    atomicAdd(&aux_acc[tid], s_p[tid]);
    atomicAdd(&aux_acc[NE + tid], s_c[tid]);
  }
}

// ---------------- offsets (prefix sum over 8) + aux loss ----------------
__global__ void k_finalize(const int* __restrict__ counts, int* __restrict__ offsets,
                           int* __restrict__ cursors, const float* __restrict__ aux_acc,
                           float* __restrict__ out_aux) {
  if (threadIdx.x == 0 && blockIdx.x == 0) {
    int off = 0;
    for (int e = 0; e < NE; e++) { offsets[e] = off; cursors[e] = off; off += counts[e]; }
    const float invN = 1.f / (float)NTOK;
    float aux = 0.f;
    for (int e = 0; e < NE; e++) aux += (aux_acc[e] * invN) * (aux_acc[NE + e] * invN);
    out_aux[0] = 0.01f * (float)NE * aux;
  }
}

// ---------------- build compacted per-expert token lists (+ inverse positions) ----------------
__global__ __launch_bounds__(256) void k_build(
    const int* __restrict__ route_e, const float* __restrict__ route_w,
    int* __restrict__ cursors, int* __restrict__ tok, float* __restrict__ wgt,
    int* __restrict__ pos) {
  __shared__ int s_cnt[NE];
  __shared__ int s_base[NE];
  int tid = threadIdx.x;
  if (tid < NE) s_cnt[tid] = 0;
  __syncthreads();
  int n = blockIdx.x * 256 + tid;
  int re = route_e[n];
  int e0 = re & 0xff, e1 = (re >> 8) & 0xff;
  float w0 = route_w[2 * n], w1 = route_w[2 * n + 1];
  int p0 = atomicAdd(&s_cnt[e0], 1);
  int p1 = atomicAdd(&s_cnt[e1], 1);
  __syncthreads();
  if (tid < NE) s_base[tid] = atomicAdd(&cursors[tid], s_cnt[tid]);
  __syncthreads();
  int g0 = s_base[e0] + p0, g1 = s_base[e1] + p1;
  tok[g0] = n; wgt[g0] = w0; pos[n] = g0;
  tok[g1] = n; wgt[g1] = w1; pos[NTOK + n] = g1;
}

// ---------------- fused FFN: yb[row,:] = w * (gelu(X @ w1 + b1) @ w2 + b2) ----------------
// 1024 threads = 16 waves. Phase A: 4x4 wave grid (32x32 tiles), Xs/W1s LDS dbuf
// (padded stride 40). Phase B: 2x8 wave grid (64x64 tiles), A from Hs (stride 136),
// B direct global->VGPR prefetched across barriers; no phase-B barriers.
__global__ __launch_bounds__(1024, 4) void k_fused(
    const _Float16* __restrict__ xb, const _Float16* __restrict__ w1t,
    const _Float16* __restrict__ w2t, const float* __restrict__ b1,
    const float* __restrict__ b2, const int* __restrict__ counts,
    const int* __restrict__ offsets, const int* __restrict__ tok,
    const float* __restrict__ wgt, _Float16* __restrict__ yb) {
  int bid = blockIdx.x;
  int e = bid & 7;
  int tm = bid >> 3;
  int cnt = counts[e];
  if (tm * BM >= cnt) return;
  int off = offsets[e];

  __shared__ _Float16 Xs[2][SBUF];    // 20 KB
  __shared__ _Float16 W1s[2][SBUF];   // 20 KB
  __shared__ _Float16 Hs[BM * HS_STRIDE];  // 34 KB

  int tid = threadIdx.x, lane = tid & 63, wave = tid >> 6;
  int wrA = wave >> 2, wcA = wave & 3;      // phase A: 4x4 grid of 32x32
  int wrB = wave >> 3, wcB = wave & 7;      // phase B: 2x8 grid of 64x64
  int fr = lane & 15, kf = (lane >> 4) * 8;
  int rq = (lane >> 4) * 4, cq = lane & 15;

  // staging: tid<512 stages Xs (128x32 chunk), tid>=512 stages W1s
  int stx = (tid < 512);
  int st = tid & 511;
  int rowL = st >> 2, kc = (st & 3) * 8;
  int tr = tm * BM + rowL;
  int t0 = tok[off + (tr < cnt ? tr : 0)];
  const _Float16* gx = xb + (size_t)t0 * DM + kc;
  const _Float16* w1e = w1t + (size_t)e * FF * DM;  // (F, D), k contiguous
  const _Float16* w2e = w2t + (size_t)e * DM * FF;  // (D, F), k contiguous
  _Float16* sdst = (stx ? &Xs[0][0] : &W1s[0][0]) + rowL * XS_STRIDE + kc;
  const _Float16* w2base = w2e + (size_t)(wcB * 64 + fr) * FF + kf;

  floatx4 acc[4][4];
  floatx4 zero = {0.f, 0.f, 0.f, 0.f};
  #pragma unroll
  for (int i = 0; i < 4; i++)
    #pragma unroll
    for (int j = 0; j < 4; j++) acc[i][j] = zero;

  #pragma unroll 1
  for (int fb = 0; fb < NFB; fb++) {
    int fbase = fb * FBLK;
    // ======== phase A: hc = X @ W1[:, fbase:fbase+128], K = 512 ========
    floatx4 acc1[2][2];
    acc1[0][0] = zero; acc1[0][1] = zero; acc1[1][0] = zero; acc1[1][1] = zero;
    const _Float16* asrc = stx ? gx : (w1e + (size_t)(fbase + rowL) * DM + kc);
    half8 rs = *(const half8*)(asrc);
    *(half8*)(sdst) = rs;                 // buf 0, k=0
    rs = *(const half8*)(asrc + 32);      // k=1 in flight
    LGKM0_BARRIER();
    #pragma unroll
    for (int k = 0; k < 16; k++) {
      int cur = k & 1;
      if (k + 1 < 16) *(half8*)(sdst + (cur ^ 1) * SBUF) = rs;
      if (k + 2 < 16) rs = *(const half8*)(asrc + (k + 2) * 32);
      const _Float16* Ab = &Xs[cur][(wrA * 32 + fr) * XS_STRIDE + kf];
      const _Float16* Bb = &W1s[cur][(wcA * 32 + fr) * XS_STRIDE + kf];
      half8 a0 = *(const half8*)(Ab);
      half8 a1 = *(const half8*)(Ab + 16 * XS_STRIDE);
      half8 b0 = *(const half8*)(Bb);
      half8 b1v = *(const half8*)(Bb + 16 * XS_STRIDE);
      acc1[0][0] = __builtin_amdgcn_mfma_f32_16x16x32_f16(a0, b0, acc1[0][0], 0, 0, 0);
      acc1[0][1] = __builtin_amdgcn_mfma_f32_16x16x32_f16(a0, b1v, acc1[0][1], 0, 0, 0);
      acc1[1][0] = __builtin_amdgcn_mfma_f32_16x16x32_f16(a1, b0, acc1[1][0], 0, 0, 0);
      acc1[1][1] = __builtin_amdgcn_mfma_f32_16x16x32_f16(a1, b1v, acc1[1][1], 0, 0, 0);
      if (k + 1 < 16) LGKM0_BARRIER();
    }
    // issue phase-B k=0 W2 loads now: they fly across GELU + barrier
    half8 bvn[4];
    {
      const _Float16* p = w2base + fbase;
      #pragma unroll
      for (int j = 0; j < 4; j++) bvn[j] = *(const half8*)(p + (size_t)(j * 16) * FF);
    }
    // GELU + Hs write (padded stride; conflict-uniform)
    #pragma unroll
    for (int j = 0; j < 2; j++) {
      int col = wcA * 32 + j * 16 + cq;
      float bb = b1[e * FF + fbase + col];
      #pragma unroll
      for (int i = 0; i < 2; i++) {
        int row0 = wrA * 32 + i * 16 + rq;
        #pragma unroll
        for (int r = 0; r < 4; r++) {
          float v = acc1[i][j][r] + bb;
          v = 0.5f * v * (1.f + erff(v * 0.70710678118654752f));  // exact GELU
          Hs[(row0 + r) * HS_STRIDE + col] = (_Float16)v;
        }
      }
    }
    LGKM0_BARRIER();  // publish Hs
    // ======== phase B: acc += Hs @ W2[fbase:fbase+128, :], K = 128, no barriers ========
    #pragma unroll
    for (int k = 0; k < 4; k++) {
      half8 bv[4];
      #pragma unroll
      for (int j = 0; j < 4; j++) bv[j] = bvn[j];
      if (k + 1 < 4) {
        const _Float16* p = w2base + fbase + (k + 1) * 32;
        #pragma unroll
        for (int j = 0; j < 4; j++) bvn[j] = *(const half8*)(p + (size_t)(j * 16) * FF);
      }
      half8 av[4];
      #pragma unroll
      for (int i = 0; i < 4; i++)
        av[i] = *(const half8*)(&Hs[(wrB * 64 + i * 16 + fr) * HS_STRIDE + k * 32 + kf]);
      __builtin_amdgcn_s_setprio(1);
      #pragma unroll
      for (int i = 0; i < 4; i++)
        #pragma unroll
        for (int j = 0; j < 4; j++)
          acc[i][j] = __builtin_amdgcn_mfma_f32_16x16x32_f16(av[i], bv[j], acc[i][j], 0, 0, 0);
      __builtin_amdgcn_s_setprio(0);
    }
    // next fb's prologue barrier protects Hs before overwrite
  }
  // ======== epilogue: yb[off+row, :] = w * (acc + b2), fp16, non-atomic ========
  float bcol[4];
  #pragma unroll
  for (int j = 0; j < 4; j++) bcol[j] = b2[e * DM + wcB * 64 + j * 16 + cq];
  #pragma unroll
  for (int i = 0; i < 4; i++) {
    #pragma unroll
    for (int r = 0; r < 4; r++) {
      int row = tm * BM + wrB * 64 + i * 16 + rq + r;
      if (row < cnt) {
        float w = wgt[off + row];
        _Float16* yr = yb + (size_t)(off + row) * DM + wcB * 64 + cq;
        #pragma unroll
        for (int j = 0; j < 4; j++)
          yr[j * 16] = (_Float16)(w * (acc[i][j][r] + bcol[j]));
      }
    }
  }
}

// ---------------- combine: out[n,:] = yb[pos0[n],:] + yb[pos1[n],:] ----------------
__global__ __launch_bounds__(256) void k_combine(
    const _Float16* __restrict__ yb, const int* __restrict__ pos,
    float* __restrict__ out) {
  int tid = threadIdx.x, lane = tid & 63, wave = tid >> 6;
  int n = blockIdx.x * 4 + wave;  // one wave per token
  int p0 = pos[n], p1 = pos[NTOK + n];
  half8 a = *(const half8*)(yb + (size_t)p0 * DM + lane * 8);
  half8 b = *(const half8*)(yb + (size_t)p1 * DM + lane * 8);
  float4 o0, o1;
  o0.x = (float)a[0] + (float)b[0];
  o0.y = (float)a[1] + (float)b[1];
  o0.z = (float)a[2] + (float)b[2];
  o0.w = (float)a[3] + (float)b[3];
  o1.x = (float)a[4] + (float)b[4];
  o1.y = (float)a[5] + (float)b[5];
  o1.z = (float)a[6] + (float)b[6];
  o1.w = (float)a[7] + (float)b[7];
  float4* op = (float4*)(out + (size_t)n * DM + lane * 8);
  op[0] = o0; op[1] = o1;
}

extern "C" void kernel_launch(void* const* d_in, const int* in_sizes, int n_in,
                              void* d_out, int out_size, void* d_ws, size_t ws_size,
                              hipStream_t stream) {
  const float* x  = (const float*)d_in[0];
  const float* rw = (const float*)d_in[1];
  const float* w1 = (const float*)d_in[2];
  const float* b1 = (const float*)d_in[3];
  const float* w2 = (const float*)d_in[4];
  const float* b2 = (const float*)d_in[5];
  float* out = (float*)d_out;

  uint8_t* ws = (uint8_t*)d_ws;
  _Float16* xb  = (_Float16*)ws;  ws += (size_t)NTOK * DM * 2;       // 33.5 MB
  _Float16* w1t = (_Float16*)ws;  ws += (size_t)NE * FF * DM * 2;    // 16.8 MB
  _Float16* w2t = (_Float16*)ws;  ws += (size_t)NE * DM * FF * 2;    // 16.8 MB
  int*   tok     = (int*)ws;      ws += (size_t)2 * NTOK * 4;
  float* wgt     = (float*)ws;    ws += (size_t)2 * NTOK * 4;
  int*   pos     = (int*)ws;      ws += (size_t)2 * NTOK * 4;
  int*   route_e = (int*)ws;      ws += (size_t)NTOK * 4;
  float* route_w = (float*)ws;    ws += (size_t)NTOK * 8;
  int*   counts  = (int*)ws;      ws += 8 * 4;
  int*   offsets = (int*)ws;      ws += 8 * 4;
  int*   cursors = (int*)ws;      ws += 8 * 4;
  float* aux     = (float*)ws;    ws += 16 * 4;
  _Float16* yb  = (_Float16*)ws;  // 2*NTOK x DM fp16 = 67 MB weighted expert outputs

  hipMemsetAsync(counts, 0, (8 + 8 + 8 + 16) * 4, stream);  // counts..aux only

  k_transpose<<<dim3(FF / 32, DM / 32, NE), 256, 0, stream>>>(w1, w1t, DM, FF);
  k_transpose<<<dim3(DM / 32, FF / 32, NE), 256, 0, stream>>>(w2, w2t, FF, DM);
  k_router<<<NTOK / 4, 256, 0, stream>>>(x, rw, xb, route_e, route_w, counts, aux);
  k_finalize<<<1, 64, 0, stream>>>(counts, offsets, cursors, aux, out + (size_t)NTOK * DM);
  k_build<<<NTOK / 256, 256, 0, stream>>>(route_e, route_w, cursors, tok, wgt, pos);
  k_fused<<<(NTOK / BM) * NE, 1024, 0, stream>>>(
      xb, w1t, w2t, b1, b2, counts, offsets, tok, wgt, yb);
  k_combine<<<NTOK / 4, 256, 0, stream>>>(yb, pos, out);
}

// Round 3
// 1157.254 us; speedup vs baseline: 1.0427x; 1.0427x over previous
//
#include <hip/hip_runtime.h>
#include <hip/hip_fp16.h>
#include <cstdint>
#include <cstddef>

// MoE FFN, D=512 F=2048 E=8 K=2, N=32768 tokens. fp16 MFMA (32x32x16).
// Fused GEMM1+GELU+GEMM2. 512 thr / 8 waves (2x4 both phases).
// K-blocked LDS layout [kchunk][row][8halfs]: frag reads are lane-consecutive
// 16B chunks -> conflict-free. W2 direct global->VGPR (2-deep prefetch),
// phase B barrier-free. X/W1 LDS double-buffered per BK=32.
#define NTOK 32768
#define DM 512
#define FF 2048
#define NE 8
#define BM 128
#define FBLK 256
#define NFB (FF / FBLK)
#define CHX 2048   // Xs chunk bytes: 128 rows * 16B
#define CHW 4096   // W1s chunk bytes: 256 rows * 16B
#define CHH 2080   // Hs chunk bytes: 130 rows * 16B (pad 2 rows: bank stagger)
#define XSB 8192   // bytes per Xs buffer (4 chunks)
#define WSB 16384  // bytes per W1s buffer (4 chunks)

typedef _Float16 half8 __attribute__((ext_vector_type(8)));
typedef float floatx4 __attribute__((ext_vector_type(4)));
typedef float floatx16 __attribute__((ext_vector_type(16)));

#define LGKM0_BARRIER() do { \
  asm volatile("s_waitcnt lgkmcnt(0)" ::: "memory"); \
  __builtin_amdgcn_s_barrier(); \
} while (0)

// ---------------- transpose + fp32->fp16 cast: W (E,R,C) -> Wt (E,C,R) ----------------
__global__ __launch_bounds__(256) void k_transpose(const float* __restrict__ W,
                                                   _Float16* __restrict__ Wt, int R, int C) {
  __shared__ float tile[32][33];
  int e = blockIdx.z;
  int c0 = blockIdx.x * 32, r0 = blockIdx.y * 32;
  const float* Wp = W + (size_t)e * R * C;
  _Float16* Wtp = Wt + (size_t)e * R * C;
  int tx = threadIdx.x & 31, ty = threadIdx.x >> 5;
  #pragma unroll
  for (int rr = ty; rr < 32; rr += 8)
    tile[rr][tx] = Wp[(size_t)(r0 + rr) * C + c0 + tx];
  __syncthreads();
  #pragma unroll
  for (int cc = ty; cc < 32; cc += 8)
    Wtp[(size_t)(c0 + cc) * R + r0 + tx] = (_Float16)tile[tx][cc];
}

// ---------------- router: logits, top-2, softmax weights, aux accumulators, x->f16 ----------------
__global__ __launch_bounds__(256) void k_router(
    const float* __restrict__ x, const float* __restrict__ rw,
    _Float16* __restrict__ xb, int* __restrict__ route_e, float* __restrict__ route_w,
    int* __restrict__ counts, float* __restrict__ aux_acc) {
  __shared__ float s_p[NE];
  __shared__ float s_c[NE];
  __shared__ int s_cnt[NE];
  int tid = threadIdx.x, lane = tid & 63, wave = tid >> 6;
  if (tid < NE) { s_p[tid] = 0.f; s_c[tid] = 0.f; s_cnt[tid] = 0; }
  __syncthreads();
  int n = blockIdx.x * 4 + wave;  // one wave per token
  const float4* xr = (const float4*)(x + (size_t)n * DM + lane * 8);
  float4 x0 = xr[0], x1 = xr[1];
  float xv[8] = {x0.x, x0.y, x0.z, x0.w, x1.x, x1.y, x1.z, x1.w};
  float acc[NE];
  #pragma unroll
  for (int e = 0; e < NE; e++) acc[e] = 0.f;
  const float4* rwv = (const float4*)rw;  // (D, E=8) row-major: 2 float4 per row
  #pragma unroll
  for (int j = 0; j < 8; j++) {
    int d = lane * 8 + j;
    float4 r0 = rwv[d * 2], r1 = rwv[d * 2 + 1];
    float xd = xv[j];
    acc[0] += xd * r0.x; acc[1] += xd * r0.y; acc[2] += xd * r0.z; acc[3] += xd * r0.w;
    acc[4] += xd * r1.x; acc[5] += xd * r1.y; acc[6] += xd * r1.z; acc[7] += xd * r1.w;
  }
  half8 hv;
  #pragma unroll
  for (int j = 0; j < 8; j++) hv[j] = (_Float16)xv[j];
  *(half8*)(xb + (size_t)n * DM + lane * 8) = hv;
  #pragma unroll
  for (int e = 0; e < NE; e++) {
    #pragma unroll
    for (int m = 1; m < 64; m <<= 1) acc[e] += __shfl_xor(acc[e], m);
  }
  if (lane == 0) {
    int e0 = 0; float v0 = acc[0];
    for (int e = 1; e < NE; e++) if (acc[e] > v0) { v0 = acc[e]; e0 = e; }
    int e1 = (e0 == 0) ? 1 : 0; float v1 = acc[e1];
    for (int e = 0; e < NE; e++) if (e != e0 && acc[e] > v1) { v1 = acc[e]; e1 = e; }
    float w0 = 1.f / (1.f + expf(v1 - v0));
    float w1 = 1.f - w0;
    route_e[n] = e0 | (e1 << 8);
    route_w[2 * n] = w0; route_w[2 * n + 1] = w1;
    float mx = acc[0];
    for (int e = 1; e < NE; e++) mx = fmaxf(mx, acc[e]);
    float p[NE]; float s = 0.f;
    for (int e = 0; e < NE; e++) { p[e] = expf(acc[e] - mx); s += p[e]; }
    float inv = 1.f / s;
    atomicAdd(&s_cnt[e0], 1); atomicAdd(&s_cnt[e1], 1);
    for (int e = 0; e < NE; e++) atomicAdd(&s_p[e], p[e] * inv);
    atomicAdd(&s_c[e0], 1.f);
  }
  __syncthreads();
  if (tid < NE) {
    atomicAdd(&counts[tid], s_cnt[tid]);
    atomicAdd(&aux_acc[tid], s_p[tid]);
    atomicAdd(&aux_acc[NE + tid], s_c[tid]);
  }
}

// ---------------- offsets (prefix sum over 8) + aux loss ----------------
__global__ void k_finalize(const int* __restrict__ counts, int* __restrict__ offsets,
                           int* __restrict__ cursors, const float* __restrict__ aux_acc,
                           float* __restrict__ out_aux) {
  if (threadIdx.x == 0 && blockIdx.x == 0) {
    int off = 0;
    for (int e = 0; e < NE; e++) { offsets[e] = off; cursors[e] = off; off += counts[e]; }
    const float invN = 1.f / (float)NTOK;
    float aux = 0.f;
    for (int e = 0; e < NE; e++) aux += (aux_acc[e] * invN) * (aux_acc[NE + e] * invN);
    out_aux[0] = 0.01f * (float)NE * aux;
  }
}

// ---------------- build compacted per-expert token lists (+ inverse positions) ----------------
__global__ __launch_bounds__(256) void k_build(
    const int* __restrict__ route_e, const float* __restrict__ route_w,
    int* __restrict__ cursors, int* __restrict__ tok, float* __restrict__ wgt,
    int* __restrict__ pos) {
  __shared__ int s_cnt[NE];
  __shared__ int s_base[NE];
  int tid = threadIdx.x;
  if (tid < NE) s_cnt[tid] = 0;
  __syncthreads();
  int n = blockIdx.x * 256 + tid;
  int re = route_e[n];
  int e0 = re & 0xff, e1 = (re >> 8) & 0xff;
  float w0 = route_w[2 * n], w1 = route_w[2 * n + 1];
  int p0 = atomicAdd(&s_cnt[e0], 1);
  int p1 = atomicAdd(&s_cnt[e1], 1);
  __syncthreads();
  if (tid < NE) s_base[tid] = atomicAdd(&cursors[tid], s_cnt[tid]);
  __syncthreads();
  int g0 = s_base[e0] + p0, g1 = s_base[e1] + p1;
  tok[g0] = n; wgt[g0] = w0; pos[n] = g0;
  tok[g1] = n; wgt[g1] = w1; pos[NTOK + n] = g1;
}

// ---------------- fused FFN: yb[row,:] = w * (gelu(X @ w1 + b1) @ w2 + b2) ----------------
__global__ __launch_bounds__(512, 2) void k_fused(
    const _Float16* __restrict__ xb, const _Float16* __restrict__ w1t,
    const _Float16* __restrict__ w2t, const float* __restrict__ b1,
    const float* __restrict__ b2, const int* __restrict__ counts,
    const int* __restrict__ offsets, const int* __restrict__ tok,
    const float* __restrict__ wgt, _Float16* __restrict__ yb) {
  int bid = blockIdx.x;
  int e = bid & 7;
  int tm = bid >> 3;
  int cnt = counts[e];
  if (tm * BM >= cnt) return;
  int off = offsets[e];

  __shared__ _Float16 Xs[2][XSB / 2];   // 16 KB, blocked [4][128][8]
  __shared__ _Float16 W1s[2][WSB / 2];  // 32 KB, blocked [4][256][8]
  __shared__ _Float16 Hs[32 * 130 * 8]; // 65 KB, blocked [32][130][8]

  int tid = threadIdx.x, lane = tid & 63, wave = tid >> 6;
  int wr = wave >> 2, wc = wave & 3;   // 2x4 wave grid (both phases)
  int l31 = lane & 31, lh = lane >> 5;

  // staging assignments
  int rowL = tid >> 2, cX = tid & 3;       // X: 128 rows x 4 chunks
  int fcW = tid & 255, cW0 = tid >> 8;     // W1: 256 rows, chunks {cW0, cW0+2}
  int tr = tm * BM + rowL;
  int t0 = tok[off + (tr < cnt ? tr : 0)];
  const _Float16* gx = xb + (size_t)t0 * DM + cX * 8;
  const _Float16* w1e = w1t + (size_t)e * FF * DM;  // (F, D), k contiguous
  const _Float16* w2e = w2t + (size_t)e * DM * FF;  // (D, F), k contiguous

  // LDS byte offsets
  int xw_off = cX * CHX + rowL * 16;                // X stage dest (within buffer)
  int ww_off = cW0 * CHW + fcW * 16;                // W1 stage dest
  int xs_r = lh * CHX + (wr * 64 + l31) * 16;       // phase A A-frag base
  int ws_r = lh * CHW + (wc * 64 + l31) * 16;       // phase A B-frag base
  int hs_r = lh * CHH + (wr * 64 + l31) * 16;       // phase B A-frag base
  int hw_lane = (l31 >> 3) * CHH + (l31 & 7) * 2 + lh * 64;  // GELU store lane part
  const _Float16* w2b = w2e + (size_t)(wc * 128 + l31) * FF + lh * 8;

  floatx16 acc[2][4];
  #pragma unroll
  for (int i = 0; i < 2; i++)
    #pragma unroll
    for (int j = 0; j < 4; j++) acc[i][j] = (floatx16)(0.f);

  #pragma unroll 1
  for (int fb = 0; fb < NFB; fb++) {
    int fbase = fb * FBLK;
    // ======== phase A: h[128][256] = X[128][512] @ W1[:, fbase:+256], BK=32 dbuf ========
    floatx16 acc1[2][2];
    acc1[0][0] = (floatx16)(0.f); acc1[0][1] = (floatx16)(0.f);
    acc1[1][0] = (floatx16)(0.f); acc1[1][1] = (floatx16)(0.f);
    const _Float16* w1p = w1e + (size_t)(fbase + fcW) * DM + cW0 * 8;
    half8 sx = *(const half8*)(gx);
    half8 sw0 = *(const half8*)(w1p);
    half8 sw1 = *(const half8*)(w1p + 16);
    *(half8*)((char*)&Xs[0][0] + xw_off) = sx;
    *(half8*)((char*)&W1s[0][0] + ww_off) = sw0;
    *(half8*)((char*)&W1s[0][0] + ww_off + 2 * CHW) = sw1;
    sx = *(const half8*)(gx + 32);
    sw0 = *(const half8*)(w1p + 32);
    sw1 = *(const half8*)(w1p + 48);
    LGKM0_BARRIER();
    #pragma unroll
    for (int k = 0; k < 16; k++) {
      int cur = k & 1;
      if (k + 1 < 16) {
        char* xd = (char*)&Xs[cur ^ 1][0];
        char* wd = (char*)&W1s[cur ^ 1][0];
        *(half8*)(xd + xw_off) = sx;
        *(half8*)(wd + ww_off) = sw0;
        *(half8*)(wd + ww_off + 2 * CHW) = sw1;
      }
      if (k + 2 < 16) {
        sx = *(const half8*)(gx + (k + 2) * 32);
        sw0 = *(const half8*)(w1p + (k + 2) * 32);
        sw1 = *(const half8*)(w1p + (k + 2) * 32 + 16);
      }
      #pragma unroll
      for (int h = 0; h < 2; h++) {
        const char* xp = (const char*)&Xs[cur][0] + h * 2 * CHX + xs_r;
        const char* wp = (const char*)&W1s[cur][0] + h * 2 * CHW + ws_r;
        half8 a0 = *(const half8*)(xp);
        half8 a1 = *(const half8*)(xp + 512);
        half8 b0 = *(const half8*)(wp);
        half8 b1v = *(const half8*)(wp + 512);
        acc1[0][0] = __builtin_amdgcn_mfma_f32_32x32x16_f16(a0, b0, acc1[0][0], 0, 0, 0);
        acc1[0][1] = __builtin_amdgcn_mfma_f32_32x32x16_f16(a0, b1v, acc1[0][1], 0, 0, 0);
        acc1[1][0] = __builtin_amdgcn_mfma_f32_32x32x16_f16(a1, b0, acc1[1][0], 0, 0, 0);
        acc1[1][1] = __builtin_amdgcn_mfma_f32_32x32x16_f16(a1, b1v, acc1[1][1], 0, 0, 0);
      }
      if (k + 1 < 16) LGKM0_BARRIER();
    }
    // prefetch W2 for phase-B kk=0,1 (in flight across GELU + barrier; lgkm wait won't drain vmcnt)
    half8 pf0[4], pf1[4];
    #pragma unroll
    for (int j = 0; j < 4; j++) {
      pf0[j] = *(const half8*)(w2b + (size_t)j * 32 * FF + fbase);
      pf1[j] = *(const half8*)(w2b + (size_t)j * 32 * FF + fbase + 16);
    }
    // GELU + blocked Hs write
    #pragma unroll
    for (int j2 = 0; j2 < 2; j2++) {
      float bb = b1[e * FF + fbase + wc * 64 + j2 * 32 + l31];
      int cbase = (wc * 8 + j2 * 4) * CHH;
      #pragma unroll
      for (int i2 = 0; i2 < 2; i2++) {
        #pragma unroll
        for (int r = 0; r < 16; r++) {
          int tokr = wr * 64 + i2 * 32 + (r & 3) + 8 * (r >> 2);
          float v = acc1[i2][j2][r] + bb;
          v = 0.5f * v * (1.f + erff(v * 0.70710678118654752f));  // exact GELU
          *(_Float16*)((char*)Hs + cbase + tokr * 16 + hw_lane) = (_Float16)v;
        }
      }
    }
    LGKM0_BARRIER();  // publish Hs
    // ======== phase B: acc += Hs[128][256] @ W2[fbase:+256, :], barrier-free ========
    #pragma unroll
    for (int kk = 0; kk < 16; kk++) {
      half8 bv[4];
      if ((kk & 1) == 0) {
        #pragma unroll
        for (int j = 0; j < 4; j++) bv[j] = pf0[j];
        if (kk + 2 < 16) {
          #pragma unroll
          for (int j = 0; j < 4; j++)
            pf0[j] = *(const half8*)(w2b + (size_t)j * 32 * FF + fbase + (kk + 2) * 16);
        }
      } else {
        #pragma unroll
        for (int j = 0; j < 4; j++) bv[j] = pf1[j];
        if (kk + 2 < 16) {
          #pragma unroll
          for (int j = 0; j < 4; j++)
            pf1[j] = *(const half8*)(w2b + (size_t)j * 32 * FF + fbase + (kk + 2) * 16);
        }
      }
      const char* hp = (const char*)Hs + kk * 2 * CHH + hs_r;
      half8 a0 = *(const half8*)(hp);
      half8 a1 = *(const half8*)(hp + 512);
      __builtin_amdgcn_s_setprio(1);
      #pragma unroll
      for (int j = 0; j < 4; j++) {
        acc[0][j] = __builtin_amdgcn_mfma_f32_32x32x16_f16(a0, bv[j], acc[0][j], 0, 0, 0);
        acc[1][j] = __builtin_amdgcn_mfma_f32_32x32x16_f16(a1, bv[j], acc[1][j], 0, 0, 0);
      }
      __builtin_amdgcn_s_setprio(0);
    }
  }
  // ======== epilogue: yb[off+row, :] = w * (acc + b2), fp16, non-atomic ========
  float bcol[4];
  #pragma unroll
  for (int j = 0; j < 4; j++) bcol[j] = b2[e * DM + wc * 128 + j * 32 + l31];
  #pragma unroll
  for (int i = 0; i < 2; i++) {
    #pragma unroll
    for (int r = 0; r < 16; r++) {
      int row = tm * BM + wr * 64 + i * 32 + (r & 3) + 8 * (r >> 2) + 4 * lh;
      if (row < cnt) {
        float w = wgt[off + row];
        _Float16* yr = yb + (size_t)(off + row) * DM + wc * 128 + l31;
        #pragma unroll
        for (int j = 0; j < 4; j++)
          yr[j * 32] = (_Float16)(w * (acc[i][j][r] + bcol[j]));
      }
    }
  }
}

// ---------------- combine: out[n,:] = yb[pos0[n],:] + yb[pos1[n],:] ----------------
__global__ __launch_bounds__(256) void k_combine(
    const _Float16* __restrict__ yb, const int* __restrict__ pos,
    float* __restrict__ out) {
  int tid = threadIdx.x, lane = tid & 63, wave = tid >> 6;
  int n = blockIdx.x * 4 + wave;  // one wave per token
  int p0 = pos[n], p1 = pos[NTOK + n];
  half8 a = *(const half8*)(yb + (size_t)p0 * DM + lane * 8);
  half8 b = *(const half8*)(yb + (size_t)p1 * DM + lane * 8);
  float4 o0, o1;
  o0.x = (float)a[0] + (float)b[0];
  o0.y = (float)a[1] + (float)b[1];
  o0.z = (float)a[2] + (float)b[2];
  o0.w = (float)a[3] + (float)b[3];
  o1.x = (float)a[4] + (float)b[4];
  o1.y = (float)a[5] + (float)b[5];
  o1.z = (float)a[6] + (float)b[6];
  o1.w = (float)a[7] + (float)b[7];
  float4* op = (float4*)(out + (size_t)n * DM + lane * 8);
  op[0] = o0; op[1] = o1;
}

extern "C" void kernel_launch(void* const* d_in, const int* in_sizes, int n_in,
                              void* d_out, int out_size, void* d_ws, size_t ws_size,
                              hipStream_t stream) {
  const float* x  = (const float*)d_in[0];
  const float* rw = (const float*)d_in[1];
  const float* w1 = (const float*)d_in[2];
  const float* b1 = (const float*)d_in[3];
  const float* w2 = (const float*)d_in[4];
  const float* b2 = (const float*)d_in[5];
  float* out = (float*)d_out;

  uint8_t* ws = (uint8_t*)d_ws;
  _Float16* xb  = (_Float16*)ws;  ws += (size_t)NTOK * DM * 2;       // 33.5 MB
  _Float16* w1t = (_Float16*)ws;  ws += (size_t)NE * FF * DM * 2;    // 16.8 MB
  _Float16* w2t = (_Float16*)ws;  ws += (size_t)NE * DM * FF * 2;    // 16.8 MB
  int*   tok     = (int*)ws;      ws += (size_t)2 * NTOK * 4;
  float* wgt     = (float*)ws;    ws += (size_t)2 * NTOK * 4;
  int*   pos     = (int*)ws;      ws += (size_t)2 * NTOK * 4;
  int*   route_e = (int*)ws;      ws += (size_t)NTOK * 4;
  float* route_w = (float*)ws;    ws += (size_t)NTOK * 8;
  int*   counts  = (int*)ws;      ws += 8 * 4;
  int*   offsets = (int*)ws;      ws += 8 * 4;
  int*   cursors = (int*)ws;      ws += 8 * 4;
  float* aux     = (float*)ws;    ws += 16 * 4;
  _Float16* yb  = (_Float16*)ws;  // 2*NTOK x DM fp16 = 67 MB weighted expert outputs

  hipMemsetAsync(counts, 0, (8 + 8 + 8 + 16) * 4, stream);  // counts..aux only

  k_transpose<<<dim3(FF / 32, DM / 32, NE), 256, 0, stream>>>(w1, w1t, DM, FF);
  k_transpose<<<dim3(DM / 32, FF / 32, NE), 256, 0, stream>>>(w2, w2t, FF, DM);
  k_router<<<NTOK / 4, 256, 0, stream>>>(x, rw, xb, route_e, route_w, counts, aux);
  k_finalize<<<1, 64, 0, stream>>>(counts, offsets, cursors, aux, out + (size_t)NTOK * DM);
  k_build<<<NTOK / 256, 256, 0, stream>>>(route_e, route_w, cursors, tok, wgt, pos);
  k_fused<<<(NTOK / BM) * NE, 512, 0, stream>>>(
      xb, w1t, w2t, b1, b2, counts, offsets, tok, wgt, yb);
  k_combine<<<NTOK / 4, 256, 0, stream>>>(yb, pos, out);
}

// Round 4
// 955.599 us; speedup vs baseline: 1.2627x; 1.2110x over previous
//
#include <hip/hip_runtime.h>
#include <hip/hip_fp16.h>
#include <cstdint>
#include <cstddef>

// MoE FFN, D=512 F=2048 E=8 K=2, N=32768 tokens. fp16 MFMA.
// Fused GEMM1+GELU+GEMM2, h in LDS (R1 structure, 702us) + chunk-XOR LDS swizzle:
// logical (row, 16B-chunk c) -> phys chunk c ^ ((row>>1)&3). Kills the 8-way
// bank conflict on all Xs/W1s/W2s fragment reads (was SQ_LDS_BANK_CONFLICT=3.8e7).
#define NTOK 32768
#define DM 512
#define FF 2048
#define NE 8
#define BM 128
#define FBLK 128
#define NFB (FF / FBLK)

typedef _Float16 half8 __attribute__((ext_vector_type(8)));
typedef float floatx4 __attribute__((ext_vector_type(4)));

#define LGKM0_BARRIER() do { \
  asm volatile("s_waitcnt lgkmcnt(0)" ::: "memory"); \
  __builtin_amdgcn_s_barrier(); \
} while (0)

// ---------------- transpose + fp32->fp16 cast: W (E,R,C) -> Wt (E,C,R) ----------------
__global__ __launch_bounds__(256) void k_transpose(const float* __restrict__ W,
                                                   _Float16* __restrict__ Wt, int R, int C) {
  __shared__ float tile[32][33];
  int e = blockIdx.z;
  int c0 = blockIdx.x * 32, r0 = blockIdx.y * 32;
  const float* Wp = W + (size_t)e * R * C;
  _Float16* Wtp = Wt + (size_t)e * R * C;
  int tx = threadIdx.x & 31, ty = threadIdx.x >> 5;
  #pragma unroll
  for (int rr = ty; rr < 32; rr += 8)
    tile[rr][tx] = Wp[(size_t)(r0 + rr) * C + c0 + tx];
  __syncthreads();
  #pragma unroll
  for (int cc = ty; cc < 32; cc += 8)
    Wtp[(size_t)(c0 + cc) * R + r0 + tx] = (_Float16)tile[tx][cc];
}

// ---------------- router: logits, top-2, softmax weights, aux accumulators, x->f16 ----------------
__global__ __launch_bounds__(256) void k_router(
    const float* __restrict__ x, const float* __restrict__ rw,
    _Float16* __restrict__ xb, int* __restrict__ route_e, float* __restrict__ route_w,
    int* __restrict__ counts, float* __restrict__ aux_acc) {
  __shared__ float s_p[NE];
  __shared__ float s_c[NE];
  __shared__ int s_cnt[NE];
  int tid = threadIdx.x, lane = tid & 63, wave = tid >> 6;
  if (tid < NE) { s_p[tid] = 0.f; s_c[tid] = 0.f; s_cnt[tid] = 0; }
  __syncthreads();
  int n = blockIdx.x * 4 + wave;  // one wave per token
  const float4* xr = (const float4*)(x + (size_t)n * DM + lane * 8);
  float4 x0 = xr[0], x1 = xr[1];
  float xv[8] = {x0.x, x0.y, x0.z, x0.w, x1.x, x1.y, x1.z, x1.w};
  float acc[NE];
  #pragma unroll
  for (int e = 0; e < NE; e++) acc[e] = 0.f;
  const float4* rwv = (const float4*)rw;  // (D, E=8) row-major: 2 float4 per row
  #pragma unroll
  for (int j = 0; j < 8; j++) {
    int d = lane * 8 + j;
    float4 r0 = rwv[d * 2], r1 = rwv[d * 2 + 1];
    float xd = xv[j];
    acc[0] += xd * r0.x; acc[1] += xd * r0.y; acc[2] += xd * r0.z; acc[3] += xd * r0.w;
    acc[4] += xd * r1.x; acc[5] += xd * r1.y; acc[6] += xd * r1.z; acc[7] += xd * r1.w;
  }
  half8 hv;
  #pragma unroll
  for (int j = 0; j < 8; j++) hv[j] = (_Float16)xv[j];
  *(half8*)(xb + (size_t)n * DM + lane * 8) = hv;
  #pragma unroll
  for (int e = 0; e < NE; e++) {
    #pragma unroll
    for (int m = 1; m < 64; m <<= 1) acc[e] += __shfl_xor(acc[e], m);
  }
  if (lane == 0) {
    int e0 = 0; float v0 = acc[0];
    for (int e = 1; e < NE; e++) if (acc[e] > v0) { v0 = acc[e]; e0 = e; }
    int e1 = (e0 == 0) ? 1 : 0; float v1 = acc[e1];
    for (int e = 0; e < NE; e++) if (e != e0 && acc[e] > v1) { v1 = acc[e]; e1 = e; }
    float w0 = 1.f / (1.f + expf(v1 - v0));
    float w1 = 1.f - w0;
    route_e[n] = e0 | (e1 << 8);
    route_w[2 * n] = w0; route_w[2 * n + 1] = w1;
    float mx = acc[0];
    for (int e = 1; e < NE; e++) mx = fmaxf(mx, acc[e]);
    float p[NE]; float s = 0.f;
    for (int e = 0; e < NE; e++) { p[e] = expf(acc[e] - mx); s += p[e]; }
    float inv = 1.f / s;
    atomicAdd(&s_cnt[e0], 1); atomicAdd(&s_cnt[e1], 1);
    for (int e = 0; e < NE; e++) atomicAdd(&s_p[e], p[e] * inv);
    atomicAdd(&s_c[e0], 1.f);
  }
  __syncthreads();
  if (tid < NE) {
    atomicAdd(&counts[tid], s_cnt[tid]);
    atomicAdd(&aux_acc[tid], s_p[tid]);
    atomicAdd(&aux_acc[NE + tid], s_c[tid]);
  }
}

// ---------------- offsets (prefix sum over 8) + aux loss ----------------
__global__ void k_finalize(const int* __restrict__ counts, int* __restrict__ offsets,
                           int* __restrict__ cursors, const float* __restrict__ aux_acc,
                           float* __restrict__ out_aux) {
  if (threadIdx.x == 0 && blockIdx.x == 0) {
    int off = 0;
    for (int e = 0; e < NE; e++) { offsets[e] = off; cursors[e] = off; off += counts[e]; }
    const float invN = 1.f / (float)NTOK;
    float aux = 0.f;
    for (int e = 0; e < NE; e++) aux += (aux_acc[e] * invN) * (aux_acc[NE + e] * invN);
    out_aux[0] = 0.01f * (float)NE * aux;
  }
}

// ---------------- build compacted per-expert token lists (+ inverse positions) ----------------
__global__ __launch_bounds__(256) void k_build(
    const int* __restrict__ route_e, const float* __restrict__ route_w,
    int* __restrict__ cursors, int* __restrict__ tok, float* __restrict__ wgt,
    int* __restrict__ pos) {
  __shared__ int s_cnt[NE];
  __shared__ int s_base[NE];
  int tid = threadIdx.x;
  if (tid < NE) s_cnt[tid] = 0;
  __syncthreads();
  int n = blockIdx.x * 256 + tid;
  int re = route_e[n];
  int e0 = re & 0xff, e1 = (re >> 8) & 0xff;
  float w0 = route_w[2 * n], w1 = route_w[2 * n + 1];
  int p0 = atomicAdd(&s_cnt[e0], 1);
  int p1 = atomicAdd(&s_cnt[e1], 1);
  __syncthreads();
  if (tid < NE) s_base[tid] = atomicAdd(&cursors[tid], s_cnt[tid]);
  __syncthreads();
  int g0 = s_base[e0] + p0, g1 = s_base[e1] + p1;
  tok[g0] = n; wgt[g0] = w0; pos[n] = g0;
  tok[g1] = n; wgt[g1] = w1; pos[NTOK + n] = g1;
}

// ---------------- fused FFN: yb[row,:] = w * (gelu(X @ w1 + b1) @ w2 + b2) ----------------
// One block = 128 gathered tokens x full D=512 output, 512 threads (8 waves, 2x4).
// F-loop in 128-chunks: GEMM1 (K=512, LDS-dbuf) -> GELU -> Hs (swizzled LDS) -> GEMM2 accumulate.
// Chunk-XOR swizzle on Xs/W1s/W2s: phys 16B-chunk = logical chunk ^ ((row>>1)&3).
// Fragment reads (16 rows at 64B stride) then cover all 32 banks at 2-way (free).
__global__ __launch_bounds__(512, 2) void k_fused(
    const _Float16* __restrict__ xb, const _Float16* __restrict__ w1t,
    const _Float16* __restrict__ w2t, const float* __restrict__ b1,
    const float* __restrict__ b2, const int* __restrict__ counts,
    const int* __restrict__ offsets, const int* __restrict__ tok,
    const float* __restrict__ wgt, _Float16* __restrict__ yb) {
  int bid = blockIdx.x;
  int e = bid & 7;
  int tm = bid >> 3;
  int cnt = counts[e];
  if (tm * BM >= cnt) return;
  int off = offsets[e];

  __shared__ _Float16 Xs[2][BM * 32];    // 16 KB
  __shared__ _Float16 W1s[2][FBLK * 32]; // 16 KB
  __shared__ _Float16 Hs[BM * FBLK];     // 32 KB, XOR-swizzled (col ^ ((row&7)<<3))
  __shared__ _Float16 W2s[2][DM * 32];   // 64 KB

  int tid = threadIdx.x, lane = tid & 63, wave = tid >> 6;
  int wr = wave >> 2, wc = wave & 3;        // 2 x 4 wave grid
  int fr = lane & 15, kfi = lane >> 4;      // frag row / k-chunk index
  int swz = (kfi ^ ((fr >> 1) & 3)) * 8;    // swizzled chunk offset (halfs), loop-invariant
  int rowL = tid >> 2, kc = (tid & 3) * 8;  // staging: 128 rows x 4 k-slots (logical)
  int stw = rowL * 32 + (((tid & 3) ^ ((tid >> 3) & 3)) * 8);  // swizzled staging dest
  int rq = (lane >> 4) * 4, cq = lane & 15; // C-layout

  int tr = tm * BM + rowL;
  int t0 = tok[off + (tr < cnt ? tr : 0)];
  const _Float16* ax = xb + (size_t)t0 * DM + kc;
  const _Float16* w1e = w1t + (size_t)e * FF * DM;  // (F, D), k contiguous
  const _Float16* w2e = w2t + (size_t)e * DM * FF;  // (D, F), k contiguous
  const _Float16* w2p = w2e + (size_t)rowL * FF + kc;

  floatx4 acc[4][8];
  floatx4 zero = {0.f, 0.f, 0.f, 0.f};
  #pragma unroll
  for (int i = 0; i < 4; i++)
    #pragma unroll
    for (int j = 0; j < 8; j++) acc[i][j] = zero;

  #pragma unroll 1
  for (int fb = 0; fb < NFB; fb++) {
    int fbase = fb * FBLK;
    // ======== phase A: hc = X @ W1[:, fbase:fbase+128], K = 512 ========
    floatx4 acc1[4][2];
    #pragma unroll
    for (int i = 0; i < 4; i++)
      #pragma unroll
      for (int j = 0; j < 2; j++) acc1[i][j] = zero;
    const _Float16* w1p = w1e + (size_t)(fbase + rowL) * DM + kc;
    half8 ra = *(const half8*)(ax);
    half8 rb = *(const half8*)(w1p);
    *(half8*)(&Xs[0][stw]) = ra;
    *(half8*)(&W1s[0][stw]) = rb;
    ra = *(const half8*)(ax + 32);
    rb = *(const half8*)(w1p + 32);
    LGKM0_BARRIER();
    #pragma unroll
    for (int k = 0; k < 16; k++) {
      int cur = k & 1;
      if (k + 1 < 16) {
        *(half8*)(&Xs[cur ^ 1][stw]) = ra;
        *(half8*)(&W1s[cur ^ 1][stw]) = rb;
      }
      if (k + 2 < 16) {
        ra = *(const half8*)(ax + (k + 2) * 32);
        rb = *(const half8*)(w1p + (k + 2) * 32);
      }
      const _Float16* Ab = &Xs[cur][(wr * 64 + fr) * 32 + swz];
      const _Float16* Bb = &W1s[cur][(wc * 32 + fr) * 32 + swz];
      half8 av[4], bv[2];
      #pragma unroll
      for (int i = 0; i < 4; i++) av[i] = *(const half8*)(Ab + i * 512);
      #pragma unroll
      for (int j = 0; j < 2; j++) bv[j] = *(const half8*)(Bb + j * 512);
      __builtin_amdgcn_s_setprio(1);
      #pragma unroll
      for (int i = 0; i < 4; i++)
        #pragma unroll
        for (int j = 0; j < 2; j++)
          acc1[i][j] = __builtin_amdgcn_mfma_f32_16x16x32_f16(av[i], bv[j], acc1[i][j], 0, 0, 0);
      __builtin_amdgcn_s_setprio(0);
      if (k + 1 < 16) LGKM0_BARRIER();
    }
    // GELU + write Hs (XOR-swizzled: col ^ ((row&7)<<3) kills the 256B-stride bank conflict)
    #pragma unroll
    for (int j = 0; j < 2; j++) {
      int col = wc * 32 + j * 16 + cq;
      float bb = b1[e * FF + fbase + col];
      #pragma unroll
      for (int i = 0; i < 4; i++) {
        #pragma unroll
        for (int r = 0; r < 4; r++) {
          int row = wr * 64 + i * 16 + rq + r;
          float v = acc1[i][j][r] + bb;
          v = 0.5f * v * (1.f + erff(v * 0.70710678118654752f));  // exact GELU
          Hs[row * FBLK + (col ^ ((row & 7) << 3))] = (_Float16)v;
        }
      }
    }
    // ======== phase B: acc += Hs @ W2[fbase:fbase+128, :], K = 128 ========
    const _Float16* w2q = w2p + fbase;
    half8 rw0 = *(const half8*)(w2q);
    half8 rw1 = *(const half8*)(w2q + (size_t)128 * FF);
    half8 rw2 = *(const half8*)(w2q + (size_t)256 * FF);
    half8 rw3 = *(const half8*)(w2q + (size_t)384 * FF);
    *(half8*)(&W2s[0][stw]) = rw0;
    *(half8*)(&W2s[0][stw + 128 * 32]) = rw1;
    *(half8*)(&W2s[0][stw + 256 * 32]) = rw2;
    *(half8*)(&W2s[0][stw + 384 * 32]) = rw3;
    rw0 = *(const half8*)(w2q + 32);
    rw1 = *(const half8*)(w2q + (size_t)128 * FF + 32);
    rw2 = *(const half8*)(w2q + (size_t)256 * FF + 32);
    rw3 = *(const half8*)(w2q + (size_t)384 * FF + 32);
    LGKM0_BARRIER();  // also publishes Hs
    #pragma unroll
    for (int k = 0; k < 4; k++) {
      int cur = k & 1;
      if (k + 1 < 4) {
        *(half8*)(&W2s[cur ^ 1][stw]) = rw0;
        *(half8*)(&W2s[cur ^ 1][stw + 128 * 32]) = rw1;
        *(half8*)(&W2s[cur ^ 1][stw + 256 * 32]) = rw2;
        *(half8*)(&W2s[cur ^ 1][stw + 384 * 32]) = rw3;
      }
      if (k + 2 < 4) {
        const _Float16* p = w2q + (k + 2) * 32;
        rw0 = *(const half8*)(p);
        rw1 = *(const half8*)(p + (size_t)128 * FF);
        rw2 = *(const half8*)(p + (size_t)256 * FF);
        rw3 = *(const half8*)(p + (size_t)384 * FF);
      }
      half8 av[4], bv[8];
      #pragma unroll
      for (int i = 0; i < 4; i++) {
        int row = wr * 64 + i * 16 + fr;
        int col = k * 32 + kfi * 8;
        av[i] = *(const half8*)(&Hs[row * FBLK + (col ^ ((row & 7) << 3))]);
      }
      const _Float16* Bb2 = &W2s[cur][(wc * 128 + fr) * 32 + swz];
      #pragma unroll
      for (int j = 0; j < 8; j++)
        bv[j] = *(const half8*)(Bb2 + j * 512);
      __builtin_amdgcn_s_setprio(1);
      #pragma unroll
      for (int i = 0; i < 4; i++)
        #pragma unroll
        for (int j = 0; j < 8; j++)
          acc[i][j] = __builtin_amdgcn_mfma_f32_16x16x32_f16(av[i], bv[j], acc[i][j], 0, 0, 0);
      __builtin_amdgcn_s_setprio(0);
      if (k + 1 < 4) LGKM0_BARRIER();
    }
  }
  // ======== epilogue: yb[off+row, :] = w * (acc + b2), fp16, non-atomic ========
  float bcol[8];
  #pragma unroll
  for (int j = 0; j < 8; j++) bcol[j] = b2[e * DM + wc * 128 + j * 16 + cq];
  #pragma unroll
  for (int i = 0; i < 4; i++) {
    #pragma unroll
    for (int r = 0; r < 4; r++) {
      int row = tm * BM + wr * 64 + i * 16 + rq + r;
      if (row < cnt) {
        float w = wgt[off + row];
        _Float16* yr = yb + (size_t)(off + row) * DM + wc * 128 + cq;
        #pragma unroll
        for (int j = 0; j < 8; j++)
          yr[j * 16] = (_Float16)(w * (acc[i][j][r] + bcol[j]));
      }
    }
  }
}

// ---------------- combine: out[n,:] = yb[pos0[n],:] + yb[pos1[n],:] ----------------
__global__ __launch_bounds__(256) void k_combine(
    const _Float16* __restrict__ yb, const int* __restrict__ pos,
    float* __restrict__ out) {
  int tid = threadIdx.x, lane = tid & 63, wave = tid >> 6;
  int n = blockIdx.x * 4 + wave;  // one wave per token
  int p0 = pos[n], p1 = pos[NTOK + n];
  half8 a = *(const half8*)(yb + (size_t)p0 * DM + lane * 8);
  half8 b = *(const half8*)(yb + (size_t)p1 * DM + lane * 8);
  float4 o0, o1;
  o0.x = (float)a[0] + (float)b[0];
  o0.y = (float)a[1] + (float)b[1];
  o0.z = (float)a[2] + (float)b[2];
  o0.w = (float)a[3] + (float)b[3];
  o1.x = (float)a[4] + (float)b[4];
  o1.y = (float)a[5] + (float)b[5];
  o1.z = (float)a[6] + (float)b[6];
  o1.w = (float)a[7] + (float)b[7];
  float4* op = (float4*)(out + (size_t)n * DM + lane * 8);
  op[0] = o0; op[1] = o1;
}

extern "C" void kernel_launch(void* const* d_in, const int* in_sizes, int n_in,
                              void* d_out, int out_size, void* d_ws, size_t ws_size,
                              hipStream_t stream) {
  const float* x  = (const float*)d_in[0];
  const float* rw = (const float*)d_in[1];
  const float* w1 = (const float*)d_in[2];
  const float* b1 = (const float*)d_in[3];
  const float* w2 = (const float*)d_in[4];
  const float* b2 = (const float*)d_in[5];
  float* out = (float*)d_out;

  uint8_t* ws = (uint8_t*)d_ws;
  _Float16* xb  = (_Float16*)ws;  ws += (size_t)NTOK * DM * 2;       // 33.5 MB
  _Float16* w1t = (_Float16*)ws;  ws += (size_t)NE * FF * DM * 2;    // 16.8 MB
  _Float16* w2t = (_Float16*)ws;  ws += (size_t)NE * DM * FF * 2;    // 16.8 MB
  int*   tok     = (int*)ws;      ws += (size_t)2 * NTOK * 4;
  float* wgt     = (float*)ws;    ws += (size_t)2 * NTOK * 4;
  int*   pos     = (int*)ws;      ws += (size_t)2 * NTOK * 4;
  int*   route_e = (int*)ws;      ws += (size_t)NTOK * 4;
  float* route_w = (float*)ws;    ws += (size_t)NTOK * 8;
  int*   counts  = (int*)ws;      ws += 8 * 4;
  int*   offsets = (int*)ws;      ws += 8 * 4;
  int*   cursors = (int*)ws;      ws += 8 * 4;
  float* aux     = (float*)ws;    ws += 16 * 4;
  _Float16* yb  = (_Float16*)ws;  // 2*NTOK x DM fp16 = 67 MB weighted expert outputs

  hipMemsetAsync(counts, 0, (8 + 8 + 8 + 16) * 4, stream);  // counts..aux only

  k_transpose<<<dim3(FF / 32, DM / 32, NE), 256, 0, stream>>>(w1, w1t, DM, FF);
  k_transpose<<<dim3(DM / 32, FF / 32, NE), 256, 0, stream>>>(w2, w2t, FF, DM);
  k_router<<<NTOK / 4, 256, 0, stream>>>(x, rw, xb, route_e, route_w, counts, aux);
  k_finalize<<<1, 64, 0, stream>>>(counts, offsets, cursors, aux, out + (size_t)NTOK * DM);
  k_build<<<NTOK / 256, 256, 0, stream>>>(route_e, route_w, cursors, tok, wgt, pos);
  k_fused<<<(NTOK / BM) * NE, 512, 0, stream>>>(
      xb, w1t, w2t, b1, b2, counts, offsets, tok, wgt, yb);
  k_combine<<<NTOK / 4, 256, 0, stream>>>(yb, pos, out);
}